// Round 1
// baseline (585.153 us; speedup 1.0000x reference)
//
#include <hip/hip_runtime.h>

// Problem constants
static constexpr int kBS    = 8;
static constexpr int kNROI  = 128;
static constexpr int kR     = kBS * kNROI;   // 1024 rows
static constexpr int kCH    = 1280;
static constexpr int kH     = 64;
static constexpr int kW     = 64;
static constexpr int kPIX   = kH * kW;       // 4096
static constexpr int kINNER = 5120;
static constexpr int kOUTC  = 1024;
static constexpr int kXE    = 2 * kOUTC;     // 2048 concat width

typedef _Float16 half8 __attribute__((ext_vector_type(8)));   // f16x8 MFMA A/B frag
typedef float floatx4 __attribute__((ext_vector_type(4)));    // MFMA C/D frag

// Async global->LDS 16B copy. LDS dest must be wave-uniform base + lane*16,
// which our chunk-index==threadIdx staging layout satisfies exactly.
__device__ __forceinline__ void gload_lds16(const _Float16* g, _Float16* l) {
    __builtin_amdgcn_global_load_lds(
        (const __attribute__((address_space(1))) void*)g,
        (__attribute__((address_space(3))) void*)l,
        16, 0, 0);
}

// ---------------------------------------------------------------------------
// Transpose+convert z: (b, c, H*W) fp32 -> zt: (b, H*W, c) f16
// ---------------------------------------------------------------------------
__global__ __launch_bounds__(256) void transpose_z_f16(const float* __restrict__ z,
                                                       _Float16* __restrict__ zt) {
    __shared__ float tile[64][33];   // [c_local][p_local]
    const int b  = blockIdx.z;
    const int p0 = blockIdx.x * 32;
    const int c0 = blockIdx.y * 64;
    const int tx = threadIdx.x;      // 0..31
    const int ty = threadIdx.y;      // 0..7
    const float* zb = z + (size_t)b * kCH * kPIX;
    _Float16* ztb = zt + (size_t)b * kPIX * kCH;
#pragma unroll
    for (int i = 0; i < 8; ++i) {
        const int cl = ty + i * 8;   // 0..63
        tile[cl][tx] = zb[(size_t)(c0 + cl) * kPIX + p0 + tx];
    }
    __syncthreads();
#pragma unroll
    for (int i = 0; i < 4; ++i) {
        const int pl = ty + i * 8;   // 0..31
        union { _Float16 h[2]; unsigned int u; } pk;
        pk.h[0] = (_Float16)tile[2 * tx][pl];
        pk.h[1] = (_Float16)tile[2 * tx + 1][pl];
        *(unsigned int*)(ztb + (size_t)(p0 + pl) * kCH + c0 + 2 * tx) = pk.u;
    }
}

// ---------------------------------------------------------------------------
// ROI point lists (separable bilinear weights)
// ---------------------------------------------------------------------------
struct RoiLists {
    int   yidx[16], xidx[16];
    float ywt[16], xwt[16];
    int   ny, nx;
    float invCount;
};

__device__ inline void build_lists(const float* __restrict__ bboxes, int r, RoiLists* L) {
    const float x1 = bboxes[r * 4 + 0] * 0.125f - 0.5f;
    const float y1 = bboxes[r * 4 + 1] * 0.125f - 0.5f;
    const float x2 = bboxes[r * 4 + 2] * 0.125f - 0.5f;
    const float y2 = bboxes[r * 4 + 3] * 0.125f - 0.5f;
    const float rw = x2 - x1, rh = y2 - y1;
    const float gwf = fminf(fmaxf(ceilf(rw), 1.0f), 8.0f);
    const float ghf = fminf(fmaxf(ceilf(rh), 1.0f), 8.0f);
    const int gw = (int)gwf, gh = (int)ghf;
    L->invCount = 1.0f / (gwf * ghf);
    for (int g = 0; g < gh; ++g) {
        const float c   = y1 + ((float)g + 0.5f) * rh / ghf;
        const bool oob  = (c < -1.0f) || (c > 64.0f);
        const float cc  = fmaxf(c, 0.0f);
        const float lo0 = floorf(cc);
        const bool hic  = (lo0 >= 63.0f);
        const int lo    = (int)fminf(lo0, 63.0f);
        const int hi    = (int)fminf(lo0 + 1.0f, 63.0f);
        const float fr  = hic ? 0.0f : (cc - lo0);
        const float m   = oob ? 0.0f : 1.0f;
        L->yidx[2 * g]     = lo; L->ywt[2 * g]     = m * (1.0f - fr);
        L->yidx[2 * g + 1] = hi; L->ywt[2 * g + 1] = m * fr;
    }
    L->ny = 2 * gh;
    for (int g = 0; g < gw; ++g) {
        const float c   = x1 + ((float)g + 0.5f) * rw / gwf;
        const bool oob  = (c < -1.0f) || (c > 64.0f);
        const float cc  = fmaxf(c, 0.0f);
        const float lo0 = floorf(cc);
        const bool hic  = (lo0 >= 63.0f);
        const int lo    = (int)fminf(lo0, 63.0f);
        const int hi    = (int)fminf(lo0 + 1.0f, 63.0f);
        const float fr  = hic ? 0.0f : (cc - lo0);
        const float m   = oob ? 0.0f : 1.0f;
        L->xidx[2 * g]     = lo; L->xwt[2 * g]     = m * (1.0f - fr);
        L->xidx[2 * g + 1] = hi; L->xwt[2 * g + 1] = m * fr;
    }
    L->nx = 2 * gw;
}

// Gather from channels-last f16 zt -> f16 x (1024 x 1280)
__global__ __launch_bounds__(256) void roi_gather_f16(const _Float16* __restrict__ zt,
                                                      const float* __restrict__ bboxes,
                                                      _Float16* __restrict__ x) {
    const int r = blockIdx.x;
    const int b = r >> 7;
    __shared__ RoiLists L;
    if (threadIdx.x == 0) build_lists(bboxes, r, &L);
    __syncthreads();
    const int ny = L.ny, nx = L.nx;
    const float ic = L.invCount;
    const _Float16* ztb = zt + (size_t)b * kPIX * kCH;
    for (int c8 = threadIdx.x; c8 < kCH / 8; c8 += 256) {
        float acc[8] = {0.f, 0.f, 0.f, 0.f, 0.f, 0.f, 0.f, 0.f};
        for (int iy = 0; iy < ny; ++iy) {
            const float wy = L.ywt[iy];
            const int Yb   = L.yidx[iy] * kW;
            for (int ix = 0; ix < nx; ++ix) {
                const float w = wy * L.xwt[ix];
                const half8 v = *(const half8*)(ztb + (size_t)(Yb + L.xidx[ix]) * kCH + c8 * 8);
#pragma unroll
                for (int q = 0; q < 8; ++q) acc[q] += w * (float)v[q];
            }
        }
        half8 o;
#pragma unroll
        for (int q = 0; q < 8; ++q) o[q] = (_Float16)(acc[q] * ic);
        *(half8*)&x[(size_t)r * kCH + c8 * 8] = o;
    }
}

// Fallback: gather directly from fp32 z (b,c,H,W) -> f16 x
__global__ __launch_bounds__(256) void roi_gather_direct(const float* __restrict__ z,
                                                         const float* __restrict__ bboxes,
                                                         _Float16* __restrict__ x) {
    const int r = blockIdx.x;
    const int b = r >> 7;
    __shared__ RoiLists L;
    if (threadIdx.x == 0) build_lists(bboxes, r, &L);
    __syncthreads();
    const int ny = L.ny, nx = L.nx;
    const float ic = L.invCount;
    const float* zb = z + (size_t)b * kCH * kPIX;
    for (int c = threadIdx.x; c < kCH; c += 256) {
        const float* zc = zb + (size_t)c * kPIX;
        float acc = 0.f;
        for (int iy = 0; iy < ny; ++iy) {
            const float wy = L.ywt[iy];
            const int base = L.yidx[iy] * kW;
            for (int ix = 0; ix < nx; ++ix)
                acc += wy * L.xwt[ix] * zc[base + L.xidx[ix]];
        }
        x[(size_t)r * kCH + c] = (_Float16)(acc * ic);
    }
}

// ---------------------------------------------------------------------------
// Weight transpose+convert: W (K x N) fp32 -> Wt (N x K) f16
// ---------------------------------------------------------------------------
__global__ __launch_bounds__(256) void convert_transpose(const float* __restrict__ W,
                                                         _Float16* __restrict__ Wt,
                                                         int K, int N) {
    __shared__ float tile[32][33];  // [k][n]
    const int n0 = blockIdx.x * 32;
    const int k0 = blockIdx.y * 32;
    const int tx = threadIdx.x;     // 0..31
    const int ty = threadIdx.y;     // 0..7
#pragma unroll
    for (int i = 0; i < 4; ++i)
        tile[ty + i * 8][tx] = W[(size_t)(k0 + ty + i * 8) * N + n0 + tx];
    __syncthreads();
#pragma unroll
    for (int i = 0; i < 4; ++i)
        Wt[(size_t)(n0 + ty + i * 8) * K + k0 + tx] = (_Float16)tile[tx][ty + i * 8];
}

// ---------------------------------------------------------------------------
// f16 MFMA GEMM (NT), 128x128 tile, BK=32, 256 threads = 4 waves.
// Staging via global_load_lds width=16 (m97 structure: stage, barrier,
// ds_read+MFMA, barrier). A: M x Kfull (row-major), Bt: N x Kfull.
//   FUSED=true : single pass over Kfull; epilogue adds bias (+ReLU) and
//                stores f16/f32 at ldc. Out = C.
//   FUSED=false: split-K partial (blockIdx.z), raw fp32 plane store. Out = P.
// ---------------------------------------------------------------------------
template <int NSPLIT, bool FUSED, bool RELU, bool F16OUT>
__global__ __launch_bounds__(256) void gemm_f16(const _Float16* __restrict__ A,
                                                const _Float16* __restrict__ Bt,
                                                const float* __restrict__ bias,
                                                void* __restrict__ Out,
                                                int Kfull, int ldc) {
    __shared__ _Float16 As[128 * 32];   // [m][k] row-major, chunk c at As[c*8]
    __shared__ _Float16 Bs[128 * 32];   // [n][k] row-major
    const int t    = threadIdx.x;
    const int lane = t & 63;
    const int wave = t >> 6;
    const int m0 = blockIdx.y * 128, n0 = blockIdx.x * 128;
    const int Ksplit = Kfull / NSPLIT;
    const int s  = FUSED ? 0 : blockIdx.z;
    const int Nn = gridDim.x * 128;
    const int Mm = gridDim.y * 128;

    // Staging: 512 16B chunks per tile; each thread stages 2 chunks of A and B.
    // Chunk c -> row c>>2, k-offset (c&3)*8. LDS dest = base + threadIdx*16B,
    // i.e. wave-uniform base + lane*16 (global_load_lds requirement).
    const int c0 = t, c1 = t + 256;
    const _Float16* Ag0 = A + (size_t)(m0 + (c0 >> 2)) * Kfull + (c0 & 3) * 8 + s * Ksplit;
    const _Float16* Ag1 = A + (size_t)(m0 + (c1 >> 2)) * Kfull + (c1 & 3) * 8 + s * Ksplit;
    const _Float16* Bg0 = Bt + (size_t)(n0 + (c0 >> 2)) * Kfull + (c0 & 3) * 8 + s * Ksplit;
    const _Float16* Bg1 = Bt + (size_t)(n0 + (c1 >> 2)) * Kfull + (c1 & 3) * 8 + s * Ksplit;
    _Float16* Al0 = &As[c0 * 8];
    _Float16* Al1 = &As[c1 * 8];
    _Float16* Bl0 = &Bs[c0 * 8];
    _Float16* Bl1 = &Bs[c1 * 8];

    const int wm = (wave >> 1) * 64;       // wave row offset in tile
    const int wn = (wave & 1) * 64;        // wave col offset in tile
    const int fm = lane & 15;              // fragment row/col within 16
    const int kq = (lane >> 4) * 8;        // fragment k offset

    floatx4 acc[4][4];
#pragma unroll
    for (int i = 0; i < 4; ++i)
#pragma unroll
        for (int j = 0; j < 4; ++j) acc[i][j] = (floatx4){0.f, 0.f, 0.f, 0.f};

    for (int k0i = 0; k0i < Ksplit; k0i += 32) {
        __syncthreads();                 // previous tile's ds_reads complete
        gload_lds16(Ag0 + k0i, Al0);
        gload_lds16(Ag1 + k0i, Al1);
        gload_lds16(Bg0 + k0i, Bl0);
        gload_lds16(Bg1 + k0i, Bl1);
        __syncthreads();                 // drains vmcnt -> LDS tile visible

        half8 af[4], bfv[4];
#pragma unroll
        for (int i = 0; i < 4; ++i)
            af[i] = *(const half8*)&As[(wm + i * 16 + fm) * 32 + kq];
#pragma unroll
        for (int j = 0; j < 4; ++j)
            bfv[j] = *(const half8*)&Bs[(wn + j * 16 + fm) * 32 + kq];
#pragma unroll
        for (int i = 0; i < 4; ++i)
#pragma unroll
            for (int j = 0; j < 4; ++j)
                acc[i][j] = __builtin_amdgcn_mfma_f32_16x16x32_f16(af[i], bfv[j], acc[i][j], 0, 0, 0);
    }

    // Epilogue. C/D layout: col = lane&15, row = (lane>>4)*4 + rr
    const int qr = (lane >> 4) * 4;
    if (FUSED) {
#pragma unroll
        for (int j = 0; j < 4; ++j) {
            const int col = n0 + wn + j * 16 + fm;
            const float bv = bias[col];
#pragma unroll
            for (int i = 0; i < 4; ++i) {
                const int row = m0 + wm + i * 16 + qr;
#pragma unroll
                for (int rr = 0; rr < 4; ++rr) {
                    float v = acc[i][j][rr] + bv;
                    if (RELU) v = fmaxf(v, 0.f);
                    if (F16OUT)
                        ((_Float16*)Out)[(size_t)(row + rr) * ldc + col] = (_Float16)v;
                    else
                        ((float*)Out)[(size_t)(row + rr) * ldc + col] = v;
                }
            }
        }
    } else {
        float* Pp = (float*)Out + (size_t)s * Mm * Nn;
#pragma unroll
        for (int j = 0; j < 4; ++j) {
            const int col = n0 + wn + j * 16 + fm;
#pragma unroll
            for (int i = 0; i < 4; ++i) {
                const int row = m0 + wm + i * 16 + qr;
#pragma unroll
                for (int rr = 0; rr < 4; ++rr)
                    Pp[(size_t)(row + rr) * Nn + col] = acc[i][j][rr];
            }
        }
    }
}

// ---------------------------------------------------------------------------
// Split-K reduce + bias + (relu) + convert.
// ---------------------------------------------------------------------------
template <bool RELU, bool F16OUT, int NSPLIT>
__global__ __launch_bounds__(256) void reduce_splitk(const float* __restrict__ P,
                                                     const float* __restrict__ bias,
                                                     void* __restrict__ Cout,
                                                     int Nn, int ldc) {
    const size_t idx = ((size_t)blockIdx.x * 256 + threadIdx.x) * 4;
    const size_t MN  = (size_t)gridDim.x * 1024;
    const int m = (int)(idx / (size_t)Nn);
    const int n = (int)(idx % (size_t)Nn);
    float4 acc = *(const float4*)(P + idx);
#pragma unroll
    for (int s = 1; s < NSPLIT; ++s) {
        const float4 v = *(const float4*)(P + (size_t)s * MN + idx);
        acc.x += v.x; acc.y += v.y; acc.z += v.z; acc.w += v.w;
    }
    const float4 b4 = *(const float4*)(bias + n);
    acc.x += b4.x; acc.y += b4.y; acc.z += b4.z; acc.w += b4.w;
    if (RELU) {
        acc.x = fmaxf(acc.x, 0.f); acc.y = fmaxf(acc.y, 0.f);
        acc.z = fmaxf(acc.z, 0.f); acc.w = fmaxf(acc.w, 0.f);
    }
    if (F16OUT) {
        union { _Float16 h[4]; uint2 u; } pk;
        pk.h[0] = (_Float16)acc.x; pk.h[1] = (_Float16)acc.y;
        pk.h[2] = (_Float16)acc.z; pk.h[3] = (_Float16)acc.w;
        *(uint2*)((_Float16*)Cout + (size_t)m * ldc + n) = pk.u;
    } else {
        *(float4*)((float*)Cout + (size_t)m * ldc + n) = acc;
    }
}

// ---------------------------------------------------------------------------
// Size-embedding MLP: 2 -> 64 -> 256 -> 1024.
// 8 ROIs per block (register-blocked rows) so S2/S3 are read once per 8 rows
// instead of once per row: L2 traffic 1.1 GB -> ~140 MB.
// ---------------------------------------------------------------------------
__global__ __launch_bounds__(256) void size_mlp8(const float* __restrict__ bboxes,
                                                 const float* __restrict__ S1,
                                                 const float* __restrict__ sb1,
                                                 const float* __restrict__ S2,
                                                 const float* __restrict__ sb2,
                                                 const float* __restrict__ S3,
                                                 const float* __restrict__ sb3,
                                                 _Float16* __restrict__ xe) {
    const int r0 = blockIdx.x * 8;
    const int t  = threadIdx.x;
    __shared__ float sz[8][2];     // [row][{h,w}]
    __shared__ float h1[8][64];
    __shared__ float h2[8][256];
    if (t < 16) {
        const int row = t >> 1;
        const int c   = t & 1;
        const float* bb = bboxes + (size_t)(r0 + row) * 4;
        sz[row][c] = (c == 0) ? (bb[3] - bb[1]) : (bb[2] - bb[0]);
    }
    __syncthreads();
    // h1: 8 rows x 64 = 512 items
#pragma unroll
    for (int i = 0; i < 2; ++i) {
        const int idx = t + i * 256;
        const int row = idx >> 6;
        const int j   = idx & 63;
        const float v = sz[row][0] * S1[j] + sz[row][1] * S1[64 + j] + sb1[j];
        h1[row][j] = fmaxf(v, 0.0f);
    }
    __syncthreads();
    // h2: j = t, all 8 rows register-blocked; S2 element loaded once per (k,j)
    {
        float acc[8];
        const float b = sb2[t];
#pragma unroll
        for (int row = 0; row < 8; ++row) acc[row] = b;
        for (int k = 0; k < 64; ++k) {
            const float w = S2[k * 256 + t];
#pragma unroll
            for (int row = 0; row < 8; ++row) acc[row] += h1[row][k] * w;
        }
#pragma unroll
        for (int row = 0; row < 8; ++row) h2[row][t] = fmaxf(acc[row], 0.0f);
    }
    __syncthreads();
    // h3: j = t + q*256, 8 rows register-blocked
#pragma unroll
    for (int q = 0; q < 4; ++q) {
        const int j = t + q * 256;
        float acc[8];
        const float b = sb3[j];
#pragma unroll
        for (int row = 0; row < 8; ++row) acc[row] = b;
        for (int k = 0; k < 256; ++k) {
            const float w = S3[k * 1024 + j];
#pragma unroll
            for (int row = 0; row < 8; ++row) acc[row] += h2[row][k] * w;
        }
#pragma unroll
        for (int row = 0; row < 8; ++row)
            xe[(size_t)(r0 + row) * kXE + kOUTC + j] = (_Float16)acc[row];
    }
}

// ---------------------------------------------------------------------------
extern "C" void kernel_launch(void* const* d_in, const int* in_sizes, int n_in,
                              void* d_out, int out_size, void* d_ws, size_t ws_size,
                              hipStream_t stream) {
    (void)in_sizes; (void)n_in; (void)out_size;
    const float* z   = (const float*)d_in[0];
    const float* bb  = (const float*)d_in[1];
    const float* W1  = (const float*)d_in[2];
    const float* b1  = (const float*)d_in[3];
    const float* W2  = (const float*)d_in[4];
    const float* b2  = (const float*)d_in[5];
    const float* S1  = (const float*)d_in[6];
    const float* sb1 = (const float*)d_in[7];
    const float* S2  = (const float*)d_in[8];
    const float* sb2 = (const float*)d_in[9];
    const float* S3  = (const float*)d_in[10];
    const float* sb3 = (const float*)d_in[11];
    const float* O   = (const float*)d_in[12];
    const float* ob  = (const float*)d_in[13];
    float* out = (float*)d_out;

    char* ws = (char*)d_ws;
    size_t off = 0;
    auto alloc = [&](size_t bytes) {
        void* p = ws + off;
        off += (bytes + 255) & ~(size_t)255;
        return p;
    };
    _Float16* x   = (_Float16*)alloc((size_t)kR * kCH * 2);       //  2.6 MB
    _Float16* h   = (_Float16*)alloc((size_t)kR * kINNER * 2);    // 10.5 MB
    _Float16* xe  = (_Float16*)alloc((size_t)kR * kXE * 2);       //  4.2 MB
    _Float16* W1t = (_Float16*)alloc((size_t)kINNER * kCH * 2);   // 13.1 MB
    _Float16* W2t = (_Float16*)alloc((size_t)kOUTC * kINNER * 2); // 10.5 MB
    _Float16* Ot  = (_Float16*)alloc((size_t)kOUTC * kXE * 2);    //  4.2 MB
    float*    P   = (float*)alloc((size_t)4 * kR * kOUTC * 4);    // 16.8 MB (max partials)
    const size_t ztBytes = (size_t)kBS * kPIX * kCH * 2;          // 83.9 MB
    _Float16* zt  = (_Float16*)(ws + off);
    const bool useT = (off + ztBytes) <= ws_size;

    // Weight conversions (fp32 -> f16, transposed to N x K)
    hipLaunchKernelGGL(convert_transpose, dim3(kINNER / 32, kCH / 32), dim3(32, 8), 0, stream,
                       W1, W1t, kCH, kINNER);
    hipLaunchKernelGGL(convert_transpose, dim3(kOUTC / 32, kINNER / 32), dim3(32, 8), 0, stream,
                       W2, W2t, kINNER, kOUTC);
    hipLaunchKernelGGL(convert_transpose, dim3(kOUTC / 32, kXE / 32), dim3(32, 8), 0, stream,
                       O, Ot, kXE, kOUTC);

    // 1) ROI-align features -> x (1024 x 1280 f16)
    if (useT) {
        hipLaunchKernelGGL(transpose_z_f16, dim3(kPIX / 32, kCH / 64, kBS), dim3(32, 8), 0,
                           stream, z, zt);
        hipLaunchKernelGGL(roi_gather_f16, dim3(kR), dim3(256), 0, stream, zt, bb, x);
    } else {
        hipLaunchKernelGGL(roi_gather_direct, dim3(kR), dim3(256), 0, stream, z, bb, x);
    }

    // 2) size-embedding MLP -> xe[:, 1024:2048] (f16)
    hipLaunchKernelGGL(size_mlp8, dim3(kR / 8), dim3(256), 0, stream,
                       bb, S1, sb1, S2, sb2, S3, sb3, xe);

    // 3) h = relu(x @ W1 + b1): (1024x1280)@(1280x5120), 320 blocks -> fused, no split-K
    hipLaunchKernelGGL((gemm_f16<1, true, true, true>),
                       dim3(kINNER / 128, kR / 128, 1), dim3(256), 0, stream,
                       x, W1t, b1, h, kCH, kINNER);

    // 4) xe[:, 0:1024] = h @ W2 + b2: (1024x5120)@(5120x1024), split-K x4 -> f16
    hipLaunchKernelGGL((gemm_f16<4, false, false, false>),
                       dim3(kOUTC / 128, kR / 128, 4), dim3(256), 0, stream,
                       h, W2t, nullptr, P, kINNER, 0);
    hipLaunchKernelGGL((reduce_splitk<false, true, 4>),
                       dim3((size_t)kR * kOUTC / 1024), dim3(256), 0, stream,
                       P, b2, xe, kOUTC, kXE);

    // 5) out = xe @ O + ob: (1024x2048)@(2048x1024), split-K x4 -> fp32
    hipLaunchKernelGGL((gemm_f16<4, false, false, false>),
                       dim3(kOUTC / 128, kR / 128, 4), dim3(256), 0, stream,
                       xe, Ot, nullptr, P, kXE, 0);
    hipLaunchKernelGGL((reduce_splitk<false, false, 4>),
                       dim3((size_t)kR * kOUTC / 1024), dim3(256), 0, stream,
                       P, ob, out, kOUTC, kOUTC);
}

// Round 2
// 471.236 us; speedup vs baseline: 1.2417x; 1.2417x over previous
//
#include <hip/hip_runtime.h>

// Problem constants
static constexpr int kBS    = 8;
static constexpr int kNROI  = 128;
static constexpr int kR     = kBS * kNROI;   // 1024 rows
static constexpr int kCH    = 1280;
static constexpr int kH     = 64;
static constexpr int kW     = 64;
static constexpr int kPIX   = kH * kW;       // 4096
static constexpr int kINNER = 5120;
static constexpr int kOUTC  = 1024;
static constexpr int kXE    = 2 * kOUTC;     // 2048 concat width
static constexpr int kE2    = 256;           // size-MLP hidden 2

typedef _Float16 half8 __attribute__((ext_vector_type(8)));   // f16x8 MFMA A/B frag
typedef float floatx4 __attribute__((ext_vector_type(4)));    // MFMA C/D frag

// Async global->LDS 16B copy. LDS dest must be wave-uniform base + lane*16,
// which our chunk-index==threadIdx staging layout satisfies exactly.
__device__ __forceinline__ void gload_lds16(const _Float16* g, _Float16* l) {
    __builtin_amdgcn_global_load_lds(
        (const __attribute__((address_space(1))) void*)g,
        (__attribute__((address_space(3))) void*)l,
        16, 0, 0);
}

// ---------------------------------------------------------------------------
// Transpose+convert z: (b, c, H*W) fp32 -> zt: (b, H*W, c) f16
// ---------------------------------------------------------------------------
__global__ __launch_bounds__(256) void transpose_z_f16(const float* __restrict__ z,
                                                       _Float16* __restrict__ zt) {
    __shared__ float tile[64][33];   // [c_local][p_local]
    const int b  = blockIdx.z;
    const int p0 = blockIdx.x * 32;
    const int c0 = blockIdx.y * 64;
    const int tx = threadIdx.x;      // 0..31
    const int ty = threadIdx.y;      // 0..7
    const float* zb = z + (size_t)b * kCH * kPIX;
    _Float16* ztb = zt + (size_t)b * kPIX * kCH;
#pragma unroll
    for (int i = 0; i < 8; ++i) {
        const int cl = ty + i * 8;   // 0..63
        tile[cl][tx] = zb[(size_t)(c0 + cl) * kPIX + p0 + tx];
    }
    __syncthreads();
#pragma unroll
    for (int i = 0; i < 4; ++i) {
        const int pl = ty + i * 8;   // 0..31
        union { _Float16 h[2]; unsigned int u; } pk;
        pk.h[0] = (_Float16)tile[2 * tx][pl];
        pk.h[1] = (_Float16)tile[2 * tx + 1][pl];
        *(unsigned int*)(ztb + (size_t)(p0 + pl) * kCH + c0 + 2 * tx) = pk.u;
    }
}

// ---------------------------------------------------------------------------
// ROI point lists (separable bilinear weights)
// ---------------------------------------------------------------------------
struct RoiLists {
    int   yidx[16], xidx[16];
    float ywt[16], xwt[16];
    int   ny, nx;
    float invCount;
};

__device__ inline void build_lists(const float* __restrict__ bboxes, int r, RoiLists* L) {
    const float x1 = bboxes[r * 4 + 0] * 0.125f - 0.5f;
    const float y1 = bboxes[r * 4 + 1] * 0.125f - 0.5f;
    const float x2 = bboxes[r * 4 + 2] * 0.125f - 0.5f;
    const float y2 = bboxes[r * 4 + 3] * 0.125f - 0.5f;
    const float rw = x2 - x1, rh = y2 - y1;
    const float gwf = fminf(fmaxf(ceilf(rw), 1.0f), 8.0f);
    const float ghf = fminf(fmaxf(ceilf(rh), 1.0f), 8.0f);
    const int gw = (int)gwf, gh = (int)ghf;
    L->invCount = 1.0f / (gwf * ghf);
    for (int g = 0; g < gh; ++g) {
        const float c   = y1 + ((float)g + 0.5f) * rh / ghf;
        const bool oob  = (c < -1.0f) || (c > 64.0f);
        const float cc  = fmaxf(c, 0.0f);
        const float lo0 = floorf(cc);
        const bool hic  = (lo0 >= 63.0f);
        const int lo    = (int)fminf(lo0, 63.0f);
        const int hi    = (int)fminf(lo0 + 1.0f, 63.0f);
        const float fr  = hic ? 0.0f : (cc - lo0);
        const float m   = oob ? 0.0f : 1.0f;
        L->yidx[2 * g]     = lo; L->ywt[2 * g]     = m * (1.0f - fr);
        L->yidx[2 * g + 1] = hi; L->ywt[2 * g + 1] = m * fr;
    }
    L->ny = 2 * gh;
    for (int g = 0; g < gw; ++g) {
        const float c   = x1 + ((float)g + 0.5f) * rw / gwf;
        const bool oob  = (c < -1.0f) || (c > 64.0f);
        const float cc  = fmaxf(c, 0.0f);
        const float lo0 = floorf(cc);
        const bool hic  = (lo0 >= 63.0f);
        const int lo    = (int)fminf(lo0, 63.0f);
        const int hi    = (int)fminf(lo0 + 1.0f, 63.0f);
        const float fr  = hic ? 0.0f : (cc - lo0);
        const float m   = oob ? 0.0f : 1.0f;
        L->xidx[2 * g]     = lo; L->xwt[2 * g]     = m * (1.0f - fr);
        L->xidx[2 * g + 1] = hi; L->xwt[2 * g + 1] = m * fr;
    }
    L->nx = 2 * gw;
}

// Gather from channels-last f16 zt -> f16 x (1024 x 1280)
__global__ __launch_bounds__(256) void roi_gather_f16(const _Float16* __restrict__ zt,
                                                      const float* __restrict__ bboxes,
                                                      _Float16* __restrict__ x) {
    const int r = blockIdx.x;
    const int b = r >> 7;
    __shared__ RoiLists L;
    if (threadIdx.x == 0) build_lists(bboxes, r, &L);
    __syncthreads();
    const int ny = L.ny, nx = L.nx;
    const float ic = L.invCount;
    const _Float16* ztb = zt + (size_t)b * kPIX * kCH;
    for (int c8 = threadIdx.x; c8 < kCH / 8; c8 += 256) {
        float acc[8] = {0.f, 0.f, 0.f, 0.f, 0.f, 0.f, 0.f, 0.f};
        for (int iy = 0; iy < ny; ++iy) {
            const float wy = L.ywt[iy];
            const int Yb   = L.yidx[iy] * kW;
            for (int ix = 0; ix < nx; ++ix) {
                const float w = wy * L.xwt[ix];
                const half8 v = *(const half8*)(ztb + (size_t)(Yb + L.xidx[ix]) * kCH + c8 * 8);
#pragma unroll
                for (int q = 0; q < 8; ++q) acc[q] += w * (float)v[q];
            }
        }
        half8 o;
#pragma unroll
        for (int q = 0; q < 8; ++q) o[q] = (_Float16)(acc[q] * ic);
        *(half8*)&x[(size_t)r * kCH + c8 * 8] = o;
    }
}

// Fallback: gather directly from fp32 z (b,c,H,W) -> f16 x
__global__ __launch_bounds__(256) void roi_gather_direct(const float* __restrict__ z,
                                                         const float* __restrict__ bboxes,
                                                         _Float16* __restrict__ x) {
    const int r = blockIdx.x;
    const int b = r >> 7;
    __shared__ RoiLists L;
    if (threadIdx.x == 0) build_lists(bboxes, r, &L);
    __syncthreads();
    const int ny = L.ny, nx = L.nx;
    const float ic = L.invCount;
    const float* zb = z + (size_t)b * kCH * kPIX;
    for (int c = threadIdx.x; c < kCH; c += 256) {
        const float* zc = zb + (size_t)c * kPIX;
        float acc = 0.f;
        for (int iy = 0; iy < ny; ++iy) {
            const float wy = L.ywt[iy];
            const int base = L.yidx[iy] * kW;
            for (int ix = 0; ix < nx; ++ix)
                acc += wy * L.xwt[ix] * zc[base + L.xidx[ix]];
        }
        x[(size_t)r * kCH + c] = (_Float16)(acc * ic);
    }
}

// ---------------------------------------------------------------------------
// Weight transpose+convert: W (K x N) fp32 -> Wt (N x K) f16
// ---------------------------------------------------------------------------
__global__ __launch_bounds__(256) void convert_transpose(const float* __restrict__ W,
                                                         _Float16* __restrict__ Wt,
                                                         int K, int N) {
    __shared__ float tile[32][33];  // [k][n]
    const int n0 = blockIdx.x * 32;
    const int k0 = blockIdx.y * 32;
    const int tx = threadIdx.x;     // 0..31
    const int ty = threadIdx.y;     // 0..7
#pragma unroll
    for (int i = 0; i < 4; ++i)
        tile[ty + i * 8][tx] = W[(size_t)(k0 + ty + i * 8) * N + n0 + tx];
    __syncthreads();
#pragma unroll
    for (int i = 0; i < 4; ++i)
        Wt[(size_t)(n0 + ty + i * 8) * K + k0 + tx] = (_Float16)tile[tx][ty + i * 8];
}

// ---------------------------------------------------------------------------
// f16 MFMA GEMM (NT), 128x128 tile, BK=32, 256 threads = 4 waves.
// Staging via global_load_lds width=16 (m97 structure). A: M x Kfull, Bt: N x Kfull.
//   FUSED=true : single pass over Kfull; epilogue adds bias (+ReLU), stores at ldc.
//   FUSED=false: split-K partial (blockIdx.z), raw fp32 plane store -> P.
// ---------------------------------------------------------------------------
template <int NSPLIT, bool FUSED, bool RELU, bool F16OUT>
__global__ __launch_bounds__(256) void gemm_f16(const _Float16* __restrict__ A,
                                                const _Float16* __restrict__ Bt,
                                                const float* __restrict__ bias,
                                                void* __restrict__ Out,
                                                int Kfull, int ldc) {
    __shared__ _Float16 As[128 * 32];   // [m][k] row-major, chunk c at As[c*8]
    __shared__ _Float16 Bs[128 * 32];   // [n][k] row-major
    const int t    = threadIdx.x;
    const int lane = t & 63;
    const int wave = t >> 6;
    const int m0 = blockIdx.y * 128, n0 = blockIdx.x * 128;
    const int Ksplit = Kfull / NSPLIT;
    const int s  = FUSED ? 0 : blockIdx.z;
    const int Nn = gridDim.x * 128;
    const int Mm = gridDim.y * 128;

    const int c0 = t, c1 = t + 256;
    const _Float16* Ag0 = A + (size_t)(m0 + (c0 >> 2)) * Kfull + (c0 & 3) * 8 + s * Ksplit;
    const _Float16* Ag1 = A + (size_t)(m0 + (c1 >> 2)) * Kfull + (c1 & 3) * 8 + s * Ksplit;
    const _Float16* Bg0 = Bt + (size_t)(n0 + (c0 >> 2)) * Kfull + (c0 & 3) * 8 + s * Ksplit;
    const _Float16* Bg1 = Bt + (size_t)(n0 + (c1 >> 2)) * Kfull + (c1 & 3) * 8 + s * Ksplit;
    _Float16* Al0 = &As[c0 * 8];
    _Float16* Al1 = &As[c1 * 8];
    _Float16* Bl0 = &Bs[c0 * 8];
    _Float16* Bl1 = &Bs[c1 * 8];

    const int wm = (wave >> 1) * 64;       // wave row offset in tile
    const int wn = (wave & 1) * 64;        // wave col offset in tile
    const int fm = lane & 15;              // fragment row/col within 16
    const int kq = (lane >> 4) * 8;        // fragment k offset

    floatx4 acc[4][4];
#pragma unroll
    for (int i = 0; i < 4; ++i)
#pragma unroll
        for (int j = 0; j < 4; ++j) acc[i][j] = (floatx4){0.f, 0.f, 0.f, 0.f};

    for (int k0i = 0; k0i < Ksplit; k0i += 32) {
        __syncthreads();                 // previous tile's ds_reads complete
        gload_lds16(Ag0 + k0i, Al0);
        gload_lds16(Ag1 + k0i, Al1);
        gload_lds16(Bg0 + k0i, Bl0);
        gload_lds16(Bg1 + k0i, Bl1);
        __syncthreads();                 // drains vmcnt -> LDS tile visible

        half8 af[4], bfv[4];
#pragma unroll
        for (int i = 0; i < 4; ++i)
            af[i] = *(const half8*)&As[(wm + i * 16 + fm) * 32 + kq];
#pragma unroll
        for (int j = 0; j < 4; ++j)
            bfv[j] = *(const half8*)&Bs[(wn + j * 16 + fm) * 32 + kq];
#pragma unroll
        for (int i = 0; i < 4; ++i)
#pragma unroll
            for (int j = 0; j < 4; ++j)
                acc[i][j] = __builtin_amdgcn_mfma_f32_16x16x32_f16(af[i], bfv[j], acc[i][j], 0, 0, 0);
    }

    // Epilogue. C/D layout: col = lane&15, row = (lane>>4)*4 + rr
    const int qr = (lane >> 4) * 4;
    if (FUSED) {
#pragma unroll
        for (int j = 0; j < 4; ++j) {
            const int col = n0 + wn + j * 16 + fm;
            const float bv = bias[col];
#pragma unroll
            for (int i = 0; i < 4; ++i) {
                const int row = m0 + wm + i * 16 + qr;
#pragma unroll
                for (int rr = 0; rr < 4; ++rr) {
                    float v = acc[i][j][rr] + bv;
                    if (RELU) v = fmaxf(v, 0.f);
                    if (F16OUT)
                        ((_Float16*)Out)[(size_t)(row + rr) * ldc + col] = (_Float16)v;
                    else
                        ((float*)Out)[(size_t)(row + rr) * ldc + col] = v;
                }
            }
        }
    } else {
        float* Pp = (float*)Out + (size_t)s * Mm * Nn;
#pragma unroll
        for (int j = 0; j < 4; ++j) {
            const int col = n0 + wn + j * 16 + fm;
#pragma unroll
            for (int i = 0; i < 4; ++i) {
                const int row = m0 + wm + i * 16 + qr;
#pragma unroll
                for (int rr = 0; rr < 4; ++rr)
                    Pp[(size_t)(row + rr) * Nn + col] = acc[i][j][rr];
            }
        }
    }
}

// ---------------------------------------------------------------------------
// Split-K reduce + bias + (relu) + convert.
// ---------------------------------------------------------------------------
template <bool RELU, bool F16OUT, int NSPLIT>
__global__ __launch_bounds__(256) void reduce_splitk(const float* __restrict__ P,
                                                     const float* __restrict__ bias,
                                                     void* __restrict__ Cout,
                                                     int Nn, int ldc) {
    const size_t idx = ((size_t)blockIdx.x * 256 + threadIdx.x) * 4;
    const size_t MN  = (size_t)gridDim.x * 1024;
    const int m = (int)(idx / (size_t)Nn);
    const int n = (int)(idx % (size_t)Nn);
    float4 acc = *(const float4*)(P + idx);
#pragma unroll
    for (int s = 1; s < NSPLIT; ++s) {
        const float4 v = *(const float4*)(P + (size_t)s * MN + idx);
        acc.x += v.x; acc.y += v.y; acc.z += v.z; acc.w += v.w;
    }
    const float4 b4 = *(const float4*)(bias + n);
    acc.x += b4.x; acc.y += b4.y; acc.z += b4.z; acc.w += b4.w;
    if (RELU) {
        acc.x = fmaxf(acc.x, 0.f); acc.y = fmaxf(acc.y, 0.f);
        acc.z = fmaxf(acc.z, 0.f); acc.w = fmaxf(acc.w, 0.f);
    }
    if (F16OUT) {
        union { _Float16 h[4]; uint2 u; } pk;
        pk.h[0] = (_Float16)acc.x; pk.h[1] = (_Float16)acc.y;
        pk.h[2] = (_Float16)acc.z; pk.h[3] = (_Float16)acc.w;
        *(uint2*)((_Float16*)Cout + (size_t)m * ldc + n) = pk.u;
    } else {
        *(float4*)((float*)Cout + (size_t)m * ldc + n) = acc;
    }
}

// ---------------------------------------------------------------------------
// Size-embedding MLP layers 1+2: 2 -> 64 -> 256, f16 out (kR x 256).
// 4 rows per block, 256 blocks -> full CU coverage; k-loop only 64 deep and
// S2 (64 KB) is L2-resident, so latency is amortized across 256 blocks.
// Layer 3 (256 -> 1024) is matmul-shaped (K=256) and runs on the MFMA GEMM.
// ---------------------------------------------------------------------------
__global__ __launch_bounds__(256) void size_mlp12(const float* __restrict__ bboxes,
                                                  const float* __restrict__ S1,
                                                  const float* __restrict__ sb1,
                                                  const float* __restrict__ S2,
                                                  const float* __restrict__ sb2,
                                                  _Float16* __restrict__ h2out) {
    const int r0 = blockIdx.x * 4;
    const int t  = threadIdx.x;
    __shared__ float sz[4][2];     // [row][{h,w}]
    __shared__ float h1[4][64];
    if (t < 8) {
        const int row = t >> 1;
        const int c   = t & 1;
        const float* bb = bboxes + (size_t)(r0 + row) * 4;
        sz[row][c] = (c == 0) ? (bb[3] - bb[1]) : (bb[2] - bb[0]);
    }
    __syncthreads();
    {   // layer 1: 4 rows x 64 = 256 items, one per thread
        const int row = t >> 6;
        const int j   = t & 63;
        const float v = sz[row][0] * S1[j] + sz[row][1] * S1[64 + j] + sb1[j];
        h1[row][j] = fmaxf(v, 0.0f);
    }
    __syncthreads();
    {   // layer 2: j = t, 4 rows register-blocked
        float acc[4];
        const float b = sb2[t];
#pragma unroll
        for (int row = 0; row < 4; ++row) acc[row] = b;
#pragma unroll 16
        for (int k = 0; k < 64; ++k) {
            const float w = S2[k * 256 + t];
#pragma unroll
            for (int row = 0; row < 4; ++row) acc[row] += h1[row][k] * w;
        }
#pragma unroll
        for (int row = 0; row < 4; ++row)
            h2out[(size_t)(r0 + row) * kE2 + t] = (_Float16)fmaxf(acc[row], 0.0f);
    }
}

// ---------------------------------------------------------------------------
extern "C" void kernel_launch(void* const* d_in, const int* in_sizes, int n_in,
                              void* d_out, int out_size, void* d_ws, size_t ws_size,
                              hipStream_t stream) {
    (void)in_sizes; (void)n_in; (void)out_size;
    const float* z   = (const float*)d_in[0];
    const float* bb  = (const float*)d_in[1];
    const float* W1  = (const float*)d_in[2];
    const float* b1  = (const float*)d_in[3];
    const float* W2  = (const float*)d_in[4];
    const float* b2  = (const float*)d_in[5];
    const float* S1  = (const float*)d_in[6];
    const float* sb1 = (const float*)d_in[7];
    const float* S2  = (const float*)d_in[8];
    const float* sb2 = (const float*)d_in[9];
    const float* S3  = (const float*)d_in[10];
    const float* sb3 = (const float*)d_in[11];
    const float* O   = (const float*)d_in[12];
    const float* ob  = (const float*)d_in[13];
    float* out = (float*)d_out;

    char* ws = (char*)d_ws;
    size_t off = 0;
    auto alloc = [&](size_t bytes) {
        void* p = ws + off;
        off += (bytes + 255) & ~(size_t)255;
        return p;
    };
    _Float16* x    = (_Float16*)alloc((size_t)kR * kCH * 2);       //  2.6 MB
    _Float16* h    = (_Float16*)alloc((size_t)kR * kINNER * 2);    // 10.5 MB
    _Float16* xe   = (_Float16*)alloc((size_t)kR * kXE * 2);       //  4.2 MB
    _Float16* W1t  = (_Float16*)alloc((size_t)kINNER * kCH * 2);   // 13.1 MB
    _Float16* W2t  = (_Float16*)alloc((size_t)kOUTC * kINNER * 2); // 10.5 MB
    _Float16* Ot   = (_Float16*)alloc((size_t)kOUTC * kXE * 2);    //  4.2 MB
    _Float16* S3t  = (_Float16*)alloc((size_t)kOUTC * kE2 * 2);    //  0.5 MB
    _Float16* h2f  = (_Float16*)alloc((size_t)kR * kE2 * 2);       //  0.5 MB
    float*    P    = (float*)alloc((size_t)4 * kR * kOUTC * 4);    // 16.8 MB (max partials)
    const size_t ztBytes = (size_t)kBS * kPIX * kCH * 2;           // 83.9 MB
    _Float16* zt  = (_Float16*)(ws + off);
    const bool useT = (off + ztBytes) <= ws_size;

    // Weight conversions (fp32 -> f16, transposed to N x K)
    hipLaunchKernelGGL(convert_transpose, dim3(kINNER / 32, kCH / 32), dim3(32, 8), 0, stream,
                       W1, W1t, kCH, kINNER);
    hipLaunchKernelGGL(convert_transpose, dim3(kOUTC / 32, kINNER / 32), dim3(32, 8), 0, stream,
                       W2, W2t, kINNER, kOUTC);
    hipLaunchKernelGGL(convert_transpose, dim3(kOUTC / 32, kXE / 32), dim3(32, 8), 0, stream,
                       O, Ot, kXE, kOUTC);
    hipLaunchKernelGGL(convert_transpose, dim3(kOUTC / 32, kE2 / 32), dim3(32, 8), 0, stream,
                       S3, S3t, kE2, kOUTC);

    // 1) ROI-align features -> x (1024 x 1280 f16)
    if (useT) {
        hipLaunchKernelGGL(transpose_z_f16, dim3(kPIX / 32, kCH / 64, kBS), dim3(32, 8), 0,
                           stream, z, zt);
        hipLaunchKernelGGL(roi_gather_f16, dim3(kR), dim3(256), 0, stream, zt, bb, x);
    } else {
        hipLaunchKernelGGL(roi_gather_direct, dim3(kR), dim3(256), 0, stream, z, bb, x);
    }

    // 2) size-embedding MLP layers 1+2 -> h2f (1024 x 256 f16)
    hipLaunchKernelGGL(size_mlp12, dim3(kR / 4), dim3(256), 0, stream,
                       bb, S1, sb1, S2, sb2, h2f);
    // 2b) layer 3 on MFMA: xe[:, 1024:2048] = h2f @ S3 + sb3
    hipLaunchKernelGGL((gemm_f16<1, true, false, true>),
                       dim3(kOUTC / 128, kR / 128, 1), dim3(256), 0, stream,
                       h2f, S3t, sb3, xe + kOUTC, kE2, kXE);

    // 3) h = relu(x @ W1 + b1): (1024x1280)@(1280x5120), 320 blocks -> fused, no split-K
    hipLaunchKernelGGL((gemm_f16<1, true, true, true>),
                       dim3(kINNER / 128, kR / 128, 1), dim3(256), 0, stream,
                       x, W1t, b1, h, kCH, kINNER);

    // 4) xe[:, 0:1024] = h @ W2 + b2: (1024x5120)@(5120x1024), split-K x4 -> f16
    hipLaunchKernelGGL((gemm_f16<4, false, false, false>),
                       dim3(kOUTC / 128, kR / 128, 4), dim3(256), 0, stream,
                       h, W2t, nullptr, P, kINNER, 0);
    hipLaunchKernelGGL((reduce_splitk<false, true, 4>),
                       dim3((size_t)kR * kOUTC / 1024), dim3(256), 0, stream,
                       P, b2, xe, kOUTC, kXE);

    // 5) out = xe @ O + ob: (1024x2048)@(2048x1024), split-K x4 -> fp32
    hipLaunchKernelGGL((gemm_f16<4, false, false, false>),
                       dim3(kOUTC / 128, kR / 128, 4), dim3(256), 0, stream,
                       xe, Ot, nullptr, P, kXE, 0);
    hipLaunchKernelGGL((reduce_splitk<false, false, 4>),
                       dim3((size_t)kR * kOUTC / 1024), dim3(256), 0, stream,
                       P, ob, out, kOUTC, kOUTC);
}

// Round 3
// 458.821 us; speedup vs baseline: 1.2753x; 1.0271x over previous
//
#include <hip/hip_runtime.h>

// Problem constants
static constexpr int kBS    = 8;
static constexpr int kNROI  = 128;
static constexpr int kR     = kBS * kNROI;   // 1024 rows
static constexpr int kCH    = 1280;
static constexpr int kH     = 64;
static constexpr int kW     = 64;
static constexpr int kPIX   = kH * kW;       // 4096
static constexpr int kINNER = 5120;
static constexpr int kOUTC  = 1024;
static constexpr int kXE    = 2 * kOUTC;     // 2048 concat width
static constexpr int kE2    = 256;           // size-MLP hidden 2

typedef _Float16 half8 __attribute__((ext_vector_type(8)));   // f16x8 MFMA A/B frag
typedef float floatx4 __attribute__((ext_vector_type(4)));    // MFMA C/D frag

// Async global->LDS 16B copy. LDS dest must be wave-uniform base + lane*16,
// which our chunk-index==threadIdx staging layout satisfies exactly.
__device__ __forceinline__ void gload_lds16(const _Float16* g, _Float16* l) {
    __builtin_amdgcn_global_load_lds(
        (const __attribute__((address_space(1))) void*)g,
        (__attribute__((address_space(3))) void*)l,
        16, 0, 0);
}

// ---------------------------------------------------------------------------
// Transpose+convert z: (b, c, H*W) fp32 -> zt: (b, H*W, c) f16
// ---------------------------------------------------------------------------
__global__ __launch_bounds__(256) void transpose_z_f16(const float* __restrict__ z,
                                                       _Float16* __restrict__ zt) {
    __shared__ float tile[64][33];   // [c_local][p_local]
    const int b  = blockIdx.z;
    const int p0 = blockIdx.x * 32;
    const int c0 = blockIdx.y * 64;
    const int tx = threadIdx.x;      // 0..31
    const int ty = threadIdx.y;      // 0..7
    const float* zb = z + (size_t)b * kCH * kPIX;
    _Float16* ztb = zt + (size_t)b * kPIX * kCH;
#pragma unroll
    for (int i = 0; i < 8; ++i) {
        const int cl = ty + i * 8;   // 0..63
        tile[cl][tx] = zb[(size_t)(c0 + cl) * kPIX + p0 + tx];
    }
    __syncthreads();
#pragma unroll
    for (int i = 0; i < 4; ++i) {
        const int pl = ty + i * 8;   // 0..31
        union { _Float16 h[2]; unsigned int u; } pk;
        pk.h[0] = (_Float16)tile[2 * tx][pl];
        pk.h[1] = (_Float16)tile[2 * tx + 1][pl];
        *(unsigned int*)(ztb + (size_t)(p0 + pl) * kCH + c0 + 2 * tx) = pk.u;
    }
}

// ---------------------------------------------------------------------------
// ROI point lists (separable bilinear weights)
// ---------------------------------------------------------------------------
struct RoiLists {
    int   yidx[16], xidx[16];
    float ywt[16], xwt[16];
    int   ny, nx;
    float invCount;
};

__device__ inline void build_lists(const float* __restrict__ bboxes, int r, RoiLists* L) {
    const float x1 = bboxes[r * 4 + 0] * 0.125f - 0.5f;
    const float y1 = bboxes[r * 4 + 1] * 0.125f - 0.5f;
    const float x2 = bboxes[r * 4 + 2] * 0.125f - 0.5f;
    const float y2 = bboxes[r * 4 + 3] * 0.125f - 0.5f;
    const float rw = x2 - x1, rh = y2 - y1;
    const float gwf = fminf(fmaxf(ceilf(rw), 1.0f), 8.0f);
    const float ghf = fminf(fmaxf(ceilf(rh), 1.0f), 8.0f);
    const int gw = (int)gwf, gh = (int)ghf;
    L->invCount = 1.0f / (gwf * ghf);
    for (int g = 0; g < gh; ++g) {
        const float c   = y1 + ((float)g + 0.5f) * rh / ghf;
        const bool oob  = (c < -1.0f) || (c > 64.0f);
        const float cc  = fmaxf(c, 0.0f);
        const float lo0 = floorf(cc);
        const bool hic  = (lo0 >= 63.0f);
        const int lo    = (int)fminf(lo0, 63.0f);
        const int hi    = (int)fminf(lo0 + 1.0f, 63.0f);
        const float fr  = hic ? 0.0f : (cc - lo0);
        const float m   = oob ? 0.0f : 1.0f;
        L->yidx[2 * g]     = lo; L->ywt[2 * g]     = m * (1.0f - fr);
        L->yidx[2 * g + 1] = hi; L->ywt[2 * g + 1] = m * fr;
    }
    L->ny = 2 * gh;
    for (int g = 0; g < gw; ++g) {
        const float c   = x1 + ((float)g + 0.5f) * rw / gwf;
        const bool oob  = (c < -1.0f) || (c > 64.0f);
        const float cc  = fmaxf(c, 0.0f);
        const float lo0 = floorf(cc);
        const bool hic  = (lo0 >= 63.0f);
        const int lo    = (int)fminf(lo0, 63.0f);
        const int hi    = (int)fminf(lo0 + 1.0f, 63.0f);
        const float fr  = hic ? 0.0f : (cc - lo0);
        const float m   = oob ? 0.0f : 1.0f;
        L->xidx[2 * g]     = lo; L->xwt[2 * g]     = m * (1.0f - fr);
        L->xidx[2 * g + 1] = hi; L->xwt[2 * g + 1] = m * fr;
    }
    L->nx = 2 * gw;
}

// ---------------------------------------------------------------------------
// ROI gather v2 from channels-last f16 zt -> f16 x (1024 x 1280).
// Grid (5, kR): blockIdx.x = 32-chunk channel group, blockIdx.y = ROI.
// Thread = (chunk lc = t&31, point-group pg = t>>5): 8-way point split cuts
// the per-thread dependent-load chain from ~81 to ~10; 5120 blocks -> 8
// blocks/CU (32 waves) so remaining latency is TLP-hidden. LDS tree-reduce.
// ---------------------------------------------------------------------------
__global__ __launch_bounds__(256) void roi_gather_f16_v2(const _Float16* __restrict__ zt,
                                                         const float* __restrict__ bboxes,
                                                         _Float16* __restrict__ x) {
    const int r  = blockIdx.y;
    const int b  = r >> 7;
    const int cg = blockIdx.x * 32;    // base chunk (c8 units) of this block
    const int t  = threadIdx.x;
    __shared__ RoiLists L;
    __shared__ int   off[256];
    __shared__ float wt[256];
    __shared__ float accs[8][32][9];   // [pg][chunk][ch] (+1 pad col)
    if (t == 0) build_lists(bboxes, r, &L);
    __syncthreads();
    const int np = L.ny * L.nx;        // <= 256
    if (t < np) {
        const int iy = t / L.nx;
        const int ix = t - iy * L.nx;
        off[t] = (L.yidx[iy] * kW + L.xidx[ix]) * kCH;
        wt[t]  = L.ywt[iy] * L.xwt[ix];
    }
    __syncthreads();
    const int lc = t & 31;
    const int pg = t >> 5;
    const _Float16* base = zt + (size_t)b * kPIX * kCH + (size_t)(cg + lc) * 8;
    float a[8] = {0.f, 0.f, 0.f, 0.f, 0.f, 0.f, 0.f, 0.f};
    for (int p = pg; p < np; p += 8) {
        const float w = wt[p];
        const half8 v = *(const half8*)(base + off[p]);
#pragma unroll
        for (int q = 0; q < 8; ++q) a[q] += w * (float)v[q];
    }
#pragma unroll
    for (int q = 0; q < 8; ++q) accs[pg][lc][q] = a[q];
    __syncthreads();
    // reduce: thread t -> chunk rc = t>>3, channel ch = t&7 (contiguous store)
    const int rc = t >> 3, ch = t & 7;
    float s = 0.f;
#pragma unroll
    for (int g = 0; g < 8; ++g) s += accs[g][rc][ch];
    x[(size_t)r * kCH + (size_t)(cg + rc) * 8 + ch] = (_Float16)(s * L.invCount);
}

// Fallback: gather directly from fp32 z (b,c,H,W) -> f16 x
__global__ __launch_bounds__(256) void roi_gather_direct(const float* __restrict__ z,
                                                         const float* __restrict__ bboxes,
                                                         _Float16* __restrict__ x) {
    const int r = blockIdx.x;
    const int b = r >> 7;
    __shared__ RoiLists L;
    if (threadIdx.x == 0) build_lists(bboxes, r, &L);
    __syncthreads();
    const int ny = L.ny, nx = L.nx;
    const float ic = L.invCount;
    const float* zb = z + (size_t)b * kCH * kPIX;
    for (int c = threadIdx.x; c < kCH; c += 256) {
        const float* zc = zb + (size_t)c * kPIX;
        float acc = 0.f;
        for (int iy = 0; iy < ny; ++iy) {
            const float wy = L.ywt[iy];
            const int base = L.yidx[iy] * kW;
            for (int ix = 0; ix < nx; ++ix)
                acc += wy * L.xwt[ix] * zc[base + L.xidx[ix]];
        }
        x[(size_t)r * kCH + c] = (_Float16)(acc * ic);
    }
}

// ---------------------------------------------------------------------------
// Weight transpose+convert: W (K x N) fp32 -> Wt (N x K) f16
// ---------------------------------------------------------------------------
__global__ __launch_bounds__(256) void convert_transpose(const float* __restrict__ W,
                                                         _Float16* __restrict__ Wt,
                                                         int K, int N) {
    __shared__ float tile[32][33];  // [k][n]
    const int n0 = blockIdx.x * 32;
    const int k0 = blockIdx.y * 32;
    const int tx = threadIdx.x;     // 0..31
    const int ty = threadIdx.y;     // 0..7
#pragma unroll
    for (int i = 0; i < 4; ++i)
        tile[ty + i * 8][tx] = W[(size_t)(k0 + ty + i * 8) * N + n0 + tx];
    __syncthreads();
#pragma unroll
    for (int i = 0; i < 4; ++i)
        Wt[(size_t)(n0 + ty + i * 8) * K + k0 + tx] = (_Float16)tile[tx][ty + i * 8];
}

// ---------------------------------------------------------------------------
// f16 MFMA GEMM (NT), 128x128 tile, BK=32, 256 threads = 4 waves.
// DOUBLE-BUFFERED global_load_lds: stage(next) is issued before the current
// tile's ds_read+MFMA, so global latency hides under compute even at
// 1 block/CU; the single end-of-iteration __syncthreads absorbs the drain.
// Only __syncthreads() is used -> no custom-sync race risk.
//   FUSED=true : single pass over Kfull; epilogue adds bias (+ReLU), stores at ldc.
//   FUSED=false: split-K partial (blockIdx.z), raw fp32 plane store -> P.
// ---------------------------------------------------------------------------
template <int NSPLIT, bool FUSED, bool RELU, bool F16OUT>
__global__ __launch_bounds__(256) void gemm_f16(const _Float16* __restrict__ A,
                                                const _Float16* __restrict__ Bt,
                                                const float* __restrict__ bias,
                                                void* __restrict__ Out,
                                                int Kfull, int ldc) {
    __shared__ _Float16 As[2][128 * 32];   // [buf][m][k] row-major, chunk c at [c*8]
    __shared__ _Float16 Bs[2][128 * 32];   // [buf][n][k] row-major
    const int t    = threadIdx.x;
    const int lane = t & 63;
    const int wave = t >> 6;
    const int m0 = blockIdx.y * 128, n0 = blockIdx.x * 128;
    const int Ksplit = Kfull / NSPLIT;
    const int s  = FUSED ? 0 : blockIdx.z;
    const int Nn = gridDim.x * 128;
    const int Mm = gridDim.y * 128;

    const int c0 = t, c1 = t + 256;
    const _Float16* Ag0 = A + (size_t)(m0 + (c0 >> 2)) * Kfull + (c0 & 3) * 8 + s * Ksplit;
    const _Float16* Ag1 = A + (size_t)(m0 + (c1 >> 2)) * Kfull + (c1 & 3) * 8 + s * Ksplit;
    const _Float16* Bg0 = Bt + (size_t)(n0 + (c0 >> 2)) * Kfull + (c0 & 3) * 8 + s * Ksplit;
    const _Float16* Bg1 = Bt + (size_t)(n0 + (c1 >> 2)) * Kfull + (c1 & 3) * 8 + s * Ksplit;

    const int wm = (wave >> 1) * 64;       // wave row offset in tile
    const int wn = (wave & 1) * 64;        // wave col offset in tile
    const int fm = lane & 15;              // fragment row/col within 16
    const int kq = (lane >> 4) * 8;        // fragment k offset

    floatx4 acc[4][4];
#pragma unroll
    for (int i = 0; i < 4; ++i)
#pragma unroll
        for (int j = 0; j < 4; ++j) acc[i][j] = (floatx4){0.f, 0.f, 0.f, 0.f};

    const int nsteps = Ksplit / 32;

    // prologue: stage tile 0 into buf 0
    gload_lds16(Ag0, &As[0][c0 * 8]);
    gload_lds16(Ag1, &As[0][c1 * 8]);
    gload_lds16(Bg0, &Bs[0][c0 * 8]);
    gload_lds16(Bg1, &Bs[0][c1 * 8]);
    __syncthreads();

    for (int ks = 0; ks < nsteps; ++ks) {
        const int cur = ks & 1;
        if (ks + 1 < nsteps) {           // stage next tile into the other buf
            const int kn = (ks + 1) * 32;
            gload_lds16(Ag0 + kn, &As[cur ^ 1][c0 * 8]);
            gload_lds16(Ag1 + kn, &As[cur ^ 1][c1 * 8]);
            gload_lds16(Bg0 + kn, &Bs[cur ^ 1][c0 * 8]);
            gload_lds16(Bg1 + kn, &Bs[cur ^ 1][c1 * 8]);
        }
        half8 af[4], bfv[4];
#pragma unroll
        for (int i = 0; i < 4; ++i)
            af[i] = *(const half8*)&As[cur][(wm + i * 16 + fm) * 32 + kq];
#pragma unroll
        for (int j = 0; j < 4; ++j)
            bfv[j] = *(const half8*)&Bs[cur][(wn + j * 16 + fm) * 32 + kq];
#pragma unroll
        for (int i = 0; i < 4; ++i)
#pragma unroll
            for (int j = 0; j < 4; ++j)
                acc[i][j] = __builtin_amdgcn_mfma_f32_16x16x32_f16(af[i], bfv[j], acc[i][j], 0, 0, 0);
        __syncthreads();                 // drains next-stage vmcnt (mostly covered)
    }

    // Epilogue. C/D layout: col = lane&15, row = (lane>>4)*4 + rr
    const int qr = (lane >> 4) * 4;
    if (FUSED) {
#pragma unroll
        for (int j = 0; j < 4; ++j) {
            const int col = n0 + wn + j * 16 + fm;
            const float bv = bias[col];
#pragma unroll
            for (int i = 0; i < 4; ++i) {
                const int row = m0 + wm + i * 16 + qr;
#pragma unroll
                for (int rr = 0; rr < 4; ++rr) {
                    float v = acc[i][j][rr] + bv;
                    if (RELU) v = fmaxf(v, 0.f);
                    if (F16OUT)
                        ((_Float16*)Out)[(size_t)(row + rr) * ldc + col] = (_Float16)v;
                    else
                        ((float*)Out)[(size_t)(row + rr) * ldc + col] = v;
                }
            }
        }
    } else {
        float* Pp = (float*)Out + (size_t)s * Mm * Nn;
#pragma unroll
        for (int j = 0; j < 4; ++j) {
            const int col = n0 + wn + j * 16 + fm;
#pragma unroll
            for (int i = 0; i < 4; ++i) {
                const int row = m0 + wm + i * 16 + qr;
#pragma unroll
                for (int rr = 0; rr < 4; ++rr)
                    Pp[(size_t)(row + rr) * Nn + col] = acc[i][j][rr];
            }
        }
    }
}

// ---------------------------------------------------------------------------
// Split-K reduce + bias + (relu) + convert.
// ---------------------------------------------------------------------------
template <bool RELU, bool F16OUT, int NSPLIT>
__global__ __launch_bounds__(256) void reduce_splitk(const float* __restrict__ P,
                                                     const float* __restrict__ bias,
                                                     void* __restrict__ Cout,
                                                     int Nn, int ldc) {
    const size_t idx = ((size_t)blockIdx.x * 256 + threadIdx.x) * 4;
    const size_t MN  = (size_t)gridDim.x * 1024;
    const int m = (int)(idx / (size_t)Nn);
    const int n = (int)(idx % (size_t)Nn);
    float4 acc = *(const float4*)(P + idx);
#pragma unroll
    for (int s = 1; s < NSPLIT; ++s) {
        const float4 v = *(const float4*)(P + (size_t)s * MN + idx);
        acc.x += v.x; acc.y += v.y; acc.z += v.z; acc.w += v.w;
    }
    const float4 b4 = *(const float4*)(bias + n);
    acc.x += b4.x; acc.y += b4.y; acc.z += b4.z; acc.w += b4.w;
    if (RELU) {
        acc.x = fmaxf(acc.x, 0.f); acc.y = fmaxf(acc.y, 0.f);
        acc.z = fmaxf(acc.z, 0.f); acc.w = fmaxf(acc.w, 0.f);
    }
    if (F16OUT) {
        union { _Float16 h[4]; uint2 u; } pk;
        pk.h[0] = (_Float16)acc.x; pk.h[1] = (_Float16)acc.y;
        pk.h[2] = (_Float16)acc.z; pk.h[3] = (_Float16)acc.w;
        *(uint2*)((_Float16*)Cout + (size_t)m * ldc + n) = pk.u;
    } else {
        *(float4*)((float*)Cout + (size_t)m * ldc + n) = acc;
    }
}

// ---------------------------------------------------------------------------
// Size-embedding MLP layers 1+2: 2 -> 64 -> 256, f16 out (kR x 256).
// 4 rows per block, 256 blocks -> full CU coverage. Layer 3 runs on MFMA.
// ---------------------------------------------------------------------------
__global__ __launch_bounds__(256) void size_mlp12(const float* __restrict__ bboxes,
                                                  const float* __restrict__ S1,
                                                  const float* __restrict__ sb1,
                                                  const float* __restrict__ S2,
                                                  const float* __restrict__ sb2,
                                                  _Float16* __restrict__ h2out) {
    const int r0 = blockIdx.x * 4;
    const int t  = threadIdx.x;
    __shared__ float sz[4][2];     // [row][{h,w}]
    __shared__ float h1[4][64];
    if (t < 8) {
        const int row = t >> 1;
        const int c   = t & 1;
        const float* bb = bboxes + (size_t)(r0 + row) * 4;
        sz[row][c] = (c == 0) ? (bb[3] - bb[1]) : (bb[2] - bb[0]);
    }
    __syncthreads();
    {   // layer 1: 4 rows x 64 = 256 items, one per thread
        const int row = t >> 6;
        const int j   = t & 63;
        const float v = sz[row][0] * S1[j] + sz[row][1] * S1[64 + j] + sb1[j];
        h1[row][j] = fmaxf(v, 0.0f);
    }
    __syncthreads();
    {   // layer 2: j = t, 4 rows register-blocked
        float acc[4];
        const float b = sb2[t];
#pragma unroll
        for (int row = 0; row < 4; ++row) acc[row] = b;
#pragma unroll 16
        for (int k = 0; k < 64; ++k) {
            const float w = S2[k * 256 + t];
#pragma unroll
            for (int row = 0; row < 4; ++row) acc[row] += h1[row][k] * w;
        }
#pragma unroll
        for (int row = 0; row < 4; ++row)
            h2out[(size_t)(r0 + row) * kE2 + t] = (_Float16)fmaxf(acc[row], 0.0f);
    }
}

// ---------------------------------------------------------------------------
extern "C" void kernel_launch(void* const* d_in, const int* in_sizes, int n_in,
                              void* d_out, int out_size, void* d_ws, size_t ws_size,
                              hipStream_t stream) {
    (void)in_sizes; (void)n_in; (void)out_size;
    const float* z   = (const float*)d_in[0];
    const float* bb  = (const float*)d_in[1];
    const float* W1  = (const float*)d_in[2];
    const float* b1  = (const float*)d_in[3];
    const float* W2  = (const float*)d_in[4];
    const float* b2  = (const float*)d_in[5];
    const float* S1  = (const float*)d_in[6];
    const float* sb1 = (const float*)d_in[7];
    const float* S2  = (const float*)d_in[8];
    const float* sb2 = (const float*)d_in[9];
    const float* S3  = (const float*)d_in[10];
    const float* sb3 = (const float*)d_in[11];
    const float* O   = (const float*)d_in[12];
    const float* ob  = (const float*)d_in[13];
    float* out = (float*)d_out;

    char* ws = (char*)d_ws;
    size_t off = 0;
    auto alloc = [&](size_t bytes) {
        void* p = ws + off;
        off += (bytes + 255) & ~(size_t)255;
        return p;
    };
    _Float16* x    = (_Float16*)alloc((size_t)kR * kCH * 2);        //  2.6 MB
    _Float16* h    = (_Float16*)alloc((size_t)kR * kINNER * 2);     // 10.5 MB
    _Float16* xe   = (_Float16*)alloc((size_t)kR * kXE * 2);        //  4.2 MB
    _Float16* W1t  = (_Float16*)alloc((size_t)kINNER * kCH * 2);    // 13.1 MB
    _Float16* W2t  = (_Float16*)alloc((size_t)kOUTC * kINNER * 2);  // 10.5 MB
    _Float16* Ot   = (_Float16*)alloc((size_t)kOUTC * kXE * 2);     //  4.2 MB
    _Float16* S3t  = (_Float16*)alloc((size_t)kOUTC * kE2 * 2);     //  0.5 MB
    _Float16* h2f  = (_Float16*)alloc((size_t)kR * kE2 * 2);        //  0.5 MB
    float*    P    = (float*)alloc((size_t)2 * kR * kINNER * 4);    // 41.9 MB (max: gemm1 split2)
    const size_t ztBytes = (size_t)kBS * kPIX * kCH * 2;            // 83.9 MB
    _Float16* zt  = (_Float16*)(ws + off);
    const bool useT = (off + ztBytes) <= ws_size;

    // Weight conversions (fp32 -> f16, transposed to N x K)
    hipLaunchKernelGGL(convert_transpose, dim3(kINNER / 32, kCH / 32), dim3(32, 8), 0, stream,
                       W1, W1t, kCH, kINNER);
    hipLaunchKernelGGL(convert_transpose, dim3(kOUTC / 32, kINNER / 32), dim3(32, 8), 0, stream,
                       W2, W2t, kINNER, kOUTC);
    hipLaunchKernelGGL(convert_transpose, dim3(kOUTC / 32, kXE / 32), dim3(32, 8), 0, stream,
                       O, Ot, kXE, kOUTC);
    hipLaunchKernelGGL(convert_transpose, dim3(kOUTC / 32, kE2 / 32), dim3(32, 8), 0, stream,
                       S3, S3t, kE2, kOUTC);

    // 1) ROI-align features -> x (1024 x 1280 f16)
    if (useT) {
        hipLaunchKernelGGL(transpose_z_f16, dim3(kPIX / 32, kCH / 64, kBS), dim3(32, 8), 0,
                           stream, z, zt);
        hipLaunchKernelGGL(roi_gather_f16_v2, dim3(kCH / 256, kR), dim3(256), 0, stream,
                           zt, bb, x);
    } else {
        hipLaunchKernelGGL(roi_gather_direct, dim3(kR), dim3(256), 0, stream, z, bb, x);
    }

    // 2) size-embedding MLP layers 1+2 -> h2f (1024 x 256 f16)
    hipLaunchKernelGGL(size_mlp12, dim3(kR / 4), dim3(256), 0, stream,
                       bb, S1, sb1, S2, sb2, h2f);
    // 2b) layer 3 on MFMA: xe[:, 1024:2048] = h2f @ S3 + sb3, split-K x4 (256 blocks)
    hipLaunchKernelGGL((gemm_f16<4, false, false, false>),
                       dim3(kOUTC / 128, kR / 128, 4), dim3(256), 0, stream,
                       h2f, S3t, nullptr, P, kE2, 0);
    hipLaunchKernelGGL((reduce_splitk<false, true, 4>),
                       dim3((size_t)kR * kOUTC / 1024), dim3(256), 0, stream,
                       P, sb3, xe + kOUTC, kOUTC, kXE);

    // 3) h = relu(x @ W1 + b1): (1024x1280)@(1280x5120), split-K x2 -> 640 blocks
    hipLaunchKernelGGL((gemm_f16<2, false, false, false>),
                       dim3(kINNER / 128, kR / 128, 2), dim3(256), 0, stream,
                       x, W1t, nullptr, P, kCH, 0);
    hipLaunchKernelGGL((reduce_splitk<true, true, 2>),
                       dim3((size_t)kR * kINNER / 1024), dim3(256), 0, stream,
                       P, b1, h, kINNER, kINNER);

    // 4) xe[:, 0:1024] = h @ W2 + b2: (1024x5120)@(5120x1024), split-K x4
    hipLaunchKernelGGL((gemm_f16<4, false, false, false>),
                       dim3(kOUTC / 128, kR / 128, 4), dim3(256), 0, stream,
                       h, W2t, nullptr, P, kINNER, 0);
    hipLaunchKernelGGL((reduce_splitk<false, true, 4>),
                       dim3((size_t)kR * kOUTC / 1024), dim3(256), 0, stream,
                       P, b2, xe, kOUTC, kXE);

    // 5) out = xe @ O + ob: (1024x2048)@(2048x1024), split-K x4 -> fp32
    hipLaunchKernelGGL((gemm_f16<4, false, false, false>),
                       dim3(kOUTC / 128, kR / 128, 4), dim3(256), 0, stream,
                       xe, Ot, nullptr, P, kXE, 0);
    hipLaunchKernelGGL((reduce_splitk<false, false, 4>),
                       dim3((size_t)kR * kOUTC / 1024), dim3(256), 0, stream,
                       P, ob, out, kOUTC, kOUTC);
}